// Round 1
// baseline (5425.818 us; speedup 1.0000x reference)
//
#include <hip/hip_runtime.h>
#include <hip/hip_fp16.h>
#include <hip/hip_bf16.h>

#define B_ 16
#define N_ 64
#define T_ 32
#define D_ 512
#define H_ 256
#define K_ 13
#define S_ 2048
#define G4_ 1024

typedef float f32x4 __attribute__((ext_vector_type(4)));
typedef short s16x8 __attribute__((ext_vector_type(8)));

__device__ __forceinline__ float sigm(float x){ return 1.0f/(1.0f+__expf(-x)); }
__device__ __forceinline__ float tanh_fast(float x){ return 1.0f - 2.0f/(1.0f+__expf(2.0f*x)); }

// ---------- prefix sums over segment lengths ----------
__global__ void k_prep(const int* __restrict__ length, int* __restrict__ cum, int* __restrict__ doc){
  const int b = threadIdx.x >> 6, n = threadIdx.x & 63;
  const int v = length[b*N_ + n];
  int x = v;
  #pragma unroll
  for (int d = 1; d < 64; d <<= 1){
    int y = __shfl_up(x, d);
    if (n >= d) x += y;
  }
  cum[b*N_ + n] = x - v;          // exclusive
  if (n == 63) doc[b] = x;        // doc_len
}

// ---------- cast weights: w_ih -> bf16 [2048][512]; w_hh -> f16 packed [dir][j][g][8] ----------
__global__ __launch_bounds__(256) void k_cast(const float* __restrict__ wf, const float* __restrict__ wb,
                       const float* __restrict__ hf, const float* __restrict__ hb,
                       ushort* __restrict__ wih, __half* __restrict__ whh){
  const int i = blockIdx.x*256 + threadIdx.x;
  if (i < 2*G4_*D_){
    const int dir = i / (G4_*D_); const int r = i % (G4_*D_);
    const float v = dir ? wb[r] : wf[r];
    ((__hip_bfloat16*)wih)[i] = __float2bfloat16(v);
  } else {
    const int j2 = i - 2*G4_*D_;
    if (j2 < 2*G4_*H_){
      const int dir = j2 / (G4_*H_); const int r = j2 % (G4_*H_);
      const int g = r >> 8, k = r & 255;
      const float v = (dir ? hb : hf)[r];
      whh[(size_t)dir*262144 + (size_t)(k>>3)*8192 + (size_t)g*8 + (k&7)] = __float2half(v);
    }
  }
}

// ---------- scatter source map + packed tags ----------
__global__ __launch_bounds__(256) void k_srcmap(const int* __restrict__ length, const int* __restrict__ cum,
                         const int* __restrict__ tags, int* __restrict__ src, int* __restrict__ ntag){
  const int i = blockIdx.x*256 + threadIdx.x;            // B*N*T = 32768
  const int b = i >> 11, nt = i & 2047, n = nt >> 5, t = nt & 31;
  if (t < length[b*N_ + n]){
    const int dest = cum[b*N_ + n] + t;
    src[b*S_ + dest] = nt;
    ntag[b*S_ + dest] = tags[i];
  }
}

// ---------- build packed new_x (bf16) + mask output ----------
__global__ __launch_bounds__(256) void k_newx(const float* __restrict__ x, const float* __restrict__ gcn,
                      const int* __restrict__ src, const int* __restrict__ doc,
                      ushort* __restrict__ nx, float* __restrict__ mask_out){
  const int r = blockIdx.x; const int b = r >> 11, s = r & 2047;
  const int L = doc[b];
  const int d = threadIdx.x*2;
  const float2 g2 = *(const float2*)&gcn[((size_t)(b*N_ + (s>>5)))*D_ + d];
  float v0 = g2.x, v1 = g2.y;
  if (s < L){
    const int nt = src[r];
    const float2 x2 = *(const float2*)&x[((size_t)(b*S_ + nt))*D_ + d];
    v0 += x2.x; v1 += x2.y;
  }
  __hip_bfloat16* o = (__hip_bfloat16*)nx + (size_t)r*D_ + d;
  o[0] = __float2bfloat16(v0); o[1] = __float2bfloat16(v1);
  if (threadIdx.x == 0) mask_out[r] = (s < L) ? 1.0f : 0.0f;
}

// ---------- input projection GEMM: pre[b][s][dir*1024+g] (f16), bias added ----------
__global__ __launch_bounds__(256) void k_gemm(const ushort* __restrict__ A, const ushort* __restrict__ Bw,
    const float* __restrict__ bias_f, const float* __restrict__ bias_b,
    const int* __restrict__ doc, __half* __restrict__ pre){
  const int m0 = blockIdx.x*128, n0 = blockIdx.y*128;
  const int b = m0 >> 11, s0 = m0 & 2047;
  if (s0 >= doc[b]) return;
  __shared__ __align__(16) ushort la[128*40];
  __shared__ __align__(16) ushort lb[128*40];
  const int tid = threadIdx.x, lane = tid & 63, w = tid >> 6;
  const int wr = w >> 1, wc = w & 1;
  const int fr = lane & 15, fq = lane >> 4;
  f32x4 acc[4][4] = {};
  const int srow = tid >> 1;
  const int sko  = (tid & 1)*16;
  for (int kt = 0; kt < 16; ++kt){
    const int k0 = kt*32;
    const float4 a0 = *(const float4*)&A[(size_t)(m0+srow)*512 + k0 + sko];
    const float4 a1 = *(const float4*)&A[(size_t)(m0+srow)*512 + k0 + sko + 8];
    const float4 b0 = *(const float4*)&Bw[(size_t)(n0+srow)*512 + k0 + sko];
    const float4 b1 = *(const float4*)&Bw[(size_t)(n0+srow)*512 + k0 + sko + 8];
    *(float4*)&la[srow*40 + sko]     = a0;
    *(float4*)&la[srow*40 + sko + 8] = a1;
    *(float4*)&lb[srow*40 + sko]     = b0;
    *(float4*)&lb[srow*40 + sko + 8] = b1;
    __syncthreads();
    s16x8 af[4], bfr[4];
    #pragma unroll
    for (int mi=0; mi<4; ++mi) af[mi] = *(const s16x8*)&la[(wr*64+mi*16+fr)*40 + fq*8];
    #pragma unroll
    for (int ni=0; ni<4; ++ni) bfr[ni] = *(const s16x8*)&lb[(wc*64+ni*16+fr)*40 + fq*8];
    #pragma unroll
    for (int mi=0; mi<4; ++mi){
      #pragma unroll
      for (int ni=0; ni<4; ++ni){
        acc[mi][ni] = __builtin_amdgcn_mfma_f32_16x16x32_bf16(af[mi], bfr[ni], acc[mi][ni], 0, 0, 0);
      }
    }
    __syncthreads();
  }
  #pragma unroll
  for (int ni=0; ni<4; ++ni){
    const int n = n0 + wc*64 + ni*16 + fr;
    const float bv = (n < 1024) ? bias_f[n] : bias_b[n-1024];
    #pragma unroll
    for (int mi=0; mi<4; ++mi){
      const int mb = m0 + wr*64 + mi*16 + fq*4;
      #pragma unroll
      for (int j=0; j<4; ++j)
        pre[(size_t)(mb+j)*2048 + n] = __float2half(acc[mi][ni][j] + bv);
    }
  }
}

// ---------- recurrent LSTM: one workgroup per (batch, dir) chain ----------
__global__ __launch_bounds__(1024) void k_recur(const __half* __restrict__ pre, const __half* __restrict__ whh,
    const int* __restrict__ doc, float* __restrict__ outh){
  const int chain = blockIdx.x; const int d = chain & 1, b = chain >> 1;
  const int L = doc[b];
  const int g = threadIdx.x;
  __shared__ __align__(16) __half h_sh[256];
  __shared__ float gp[1024];
  if (g < 256) h_sh[g] = __float2half(0.0f);
  float c = 0.0f;
  __syncthreads();
  const __half* wbase = whh + (size_t)d*262144 + (size_t)g*8;
  const __half* pbase = pre + (size_t)d*1024 + g;
  for (int t = 0; t < L; ++t){
    const int pos = d ? (L-1-t) : t;
    float acc = __half2float(pbase[(size_t)(b*S_ + pos)*2048]);
    __half2 a2 = __floats2half2_rn(0.f, 0.f);
    #pragma unroll
    for (int j = 0; j < 32; ++j){
      const float4 wv = *(const float4*)(wbase + (size_t)j*8192);
      const float4 hv = *(const float4*)&h_sh[j*8];
      const __half2* w2 = (const __half2*)&wv;
      const __half2* h2 = (const __half2*)&hv;
      a2 = __hfma2(w2[0], h2[0], a2);
      a2 = __hfma2(w2[1], h2[1], a2);
      a2 = __hfma2(w2[2], h2[2], a2);
      a2 = __hfma2(w2[3], h2[3], a2);
      if ((j & 3) == 3){
        acc += __low2float(a2) + __high2float(a2);
        a2 = __floats2half2_rn(0.f, 0.f);
      }
    }
    gp[g] = acc;
    __syncthreads();
    if (g < 256){
      const float gi = gp[g], gf = gp[256+g], gg = gp[512+g], go = gp[768+g];
      c = sigm(gf)*c + sigm(gi)*tanh_fast(gg);
      const float h = sigm(go)*tanh_fast(c);
      h_sh[g] = __float2half(h);
      outh[(size_t)(b*S_ + pos)*512 + d*256 + g] = h;
    }
    __syncthreads();
  }
}

// ---------- logits: wave per row ----------
__global__ __launch_bounds__(256) void k_logits(const float* __restrict__ outh, const float* __restrict__ mw,
    const float* __restrict__ mb, const int* __restrict__ doc, float* __restrict__ logits){
  const int w = threadIdx.x >> 6, lane = threadIdx.x & 63;
  const int r = blockIdx.x*4 + w;
  const int b = r >> 11, s = r & 2047;
  if (s >= doc[b]){
    if (lane < 13) logits[(size_t)r*13 + lane] = mb[lane];
    return;
  }
  float xv[8];
  #pragma unroll
  for (int m=0; m<8; ++m) xv[m] = outh[(size_t)r*512 + lane + m*64];
  #pragma unroll
  for (int k=0; k<13; ++k){
    float p = 0.f;
    #pragma unroll
    for (int m=0; m<8; ++m) p += xv[m]*mw[k*512 + lane + m*64];
    #pragma unroll
    for (int off=32; off; off>>=1) p += __shfl_down(p, off);
    if (lane == 0) logits[(size_t)r*13 + k] = p + mb[k];
  }
}

// ---------- CRF: one wave per batch ----------
__global__ void k_crf(const float* __restrict__ logits, const int* __restrict__ ntag,
    const int* __restrict__ doc, const float* __restrict__ trans,
    const float* __restrict__ stt, const float* __restrict__ ent, float* __restrict__ ll){
  const int b = blockIdx.x, lane = threadIdx.x;
  const int L = doc[b];
  const float* lg = logits + (size_t)b*S_*13;
  float tc[13];
  #pragma unroll
  for (int i=0; i<13; ++i) tc[i] = (lane < 13) ? trans[i*13 + lane] : 0.f;
  float alpha = (lane < 13) ? (stt[lane] + lg[lane]) : -1e30f;
  for (int t=1; t<L; ++t){
    const float e = (lane < 13) ? lg[(size_t)t*13 + lane] : 0.f;
    float v[13]; float m = -1e30f;
    #pragma unroll
    for (int i=0; i<13; ++i){ v[i] = __shfl(alpha, i) + tc[i]; m = fmaxf(m, v[i]); }
    float sum = 0.f;
    #pragma unroll
    for (int i=0; i<13; ++i) sum += __expf(v[i] - m);
    alpha = m + __logf(sum) + e;
  }
  float av = (lane < 13) ? alpha + ent[lane] : -1e30f;
  float m2 = -1e30f;
  #pragma unroll
  for (int i=0; i<13; ++i) m2 = fmaxf(m2, __shfl(av, i));
  float s2 = 0.f;
  #pragma unroll
  for (int i=0; i<13; ++i) s2 += __expf(__shfl(av, i) - m2);
  const float logz = m2 + __logf(s2);
  const int* tg = ntag + (size_t)b*S_;
  float num = 0.f;
  for (int t = lane; t < L; t += 64){
    const int cur = tg[t];
    num += lg[(size_t)t*13 + cur];
    if (t >= 1) num += trans[tg[t-1]*13 + cur];
  }
  #pragma unroll
  for (int off=32; off; off>>=1) num += __shfl_down(num, off);
  if (lane == 0){
    num += stt[tg[0]] + ent[tg[L-1]];
    ll[b] = num - logz;
  }
}

extern "C" void kernel_launch(void* const* d_in, const int* in_sizes, int n_in,
                              void* d_out, int out_size, void* d_ws, size_t ws_size,
                              hipStream_t stream){
  const float* x    = (const float*)d_in[0];
  const float* gcn  = (const float*)d_in[1];
  const int* length = (const int*)d_in[3];
  const int* tags   = (const int*)d_in[4];
  const float* wihf = (const float*)d_in[5];
  const float* whhf = (const float*)d_in[6];
  const float* bf   = (const float*)d_in[7];
  const float* wihb = (const float*)d_in[8];
  const float* whhb = (const float*)d_in[9];
  const float* bb   = (const float*)d_in[10];
  const float* mw   = (const float*)d_in[11];
  const float* mb   = (const float*)d_in[12];
  const float* trans= (const float*)d_in[13];
  const float* stt  = (const float*)d_in[14];
  const float* ent  = (const float*)d_in[15];

  char* ws = (char*)d_ws;
  ushort* nx   = (ushort*)(ws + 0);              // 33,554,432 B  new_x bf16
  __half* pre  = (__half*)(ws + 33554432);       // 134,217,728 B pre-activations f16
  float*  outh = (float*)(ws + 167772160);       // 67,108,864 B  concat h states
  ushort* wih  = (ushort*)(ws + 234881024);      // 2,097,152 B   w_ih bf16 [2048][512]
  __half* whh  = (__half*)(ws + 236978176);      // 1,048,576 B   w_hh f16 packed
  int*    src  = (int*)(ws + 238026752);         // 131,072 B
  int*    ntag = (int*)(ws + 238157824);         // 131,072 B
  int*    cum  = (int*)(ws + 238288896);         // 4,096 B
  int*    doc  = (int*)(ws + 238292992);         // 64 B

  float* logits  = (float*)d_out;                // 425,984 floats
  float* maskout = logits + 425984;              // 32,768 floats
  float* ll      = maskout + 32768;              // 16 floats

  hipLaunchKernelGGL(k_prep,   dim3(1),        dim3(1024), 0, stream, length, cum, doc);
  hipLaunchKernelGGL(k_cast,   dim3(6144),     dim3(256),  0, stream, wihf, wihb, whhf, whhb, wih, whh);
  hipLaunchKernelGGL(k_srcmap, dim3(128),      dim3(256),  0, stream, length, cum, tags, src, ntag);
  hipLaunchKernelGGL(k_newx,   dim3(32768),    dim3(256),  0, stream, x, gcn, src, doc, nx, maskout);
  hipLaunchKernelGGL(k_gemm,   dim3(256, 16),  dim3(256),  0, stream, nx, wih, bf, bb, doc, pre);
  hipLaunchKernelGGL(k_recur,  dim3(32),       dim3(1024), 0, stream, pre, whh, doc, outh);
  hipLaunchKernelGGL(k_logits, dim3(8192),     dim3(256),  0, stream, outh, mw, mb, doc, logits);
  hipLaunchKernelGGL(k_crf,    dim3(16),       dim3(64),   0, stream, logits, ntag, doc, trans, stt, ent, ll);
}

// Round 2
// 4802.284 us; speedup vs baseline: 1.1298x; 1.1298x over previous
//
#include <hip/hip_runtime.h>
#include <hip/hip_fp16.h>
#include <hip/hip_bf16.h>

#define B_ 16
#define N_ 64
#define T_ 32
#define D_ 512
#define H_ 256
#define K_ 13
#define S_ 2048
#define G4_ 1024

typedef float f32x4 __attribute__((ext_vector_type(4)));
typedef short s16x8 __attribute__((ext_vector_type(8)));
typedef _Float16 f16x8 __attribute__((ext_vector_type(8)));

__device__ __forceinline__ float sigm(float x){ return 1.0f/(1.0f+__expf(-x)); }
__device__ __forceinline__ float tanh_fast(float x){ return 1.0f - 2.0f/(1.0f+__expf(2.0f*x)); }

// ---------- prefix sums over segment lengths ----------
__global__ void k_prep(const int* __restrict__ length, int* __restrict__ cum, int* __restrict__ doc){
  const int b = threadIdx.x >> 6, n = threadIdx.x & 63;
  const int v = length[b*N_ + n];
  int x = v;
  #pragma unroll
  for (int d = 1; d < 64; d <<= 1){
    int y = __shfl_up(x, d);
    if (n >= d) x += y;
  }
  cum[b*N_ + n] = x - v;          // exclusive
  if (n == 63) doc[b] = x;        // doc_len
}

// ---------- cast w_ih -> bf16 [2048][512] ----------
__global__ __launch_bounds__(256) void k_cast(const float* __restrict__ wf, const float* __restrict__ wb,
                       ushort* __restrict__ wih){
  const int i = blockIdx.x*256 + threadIdx.x;   // 2*1024*512
  const int dir = i / (G4_*D_); const int r = i % (G4_*D_);
  const float v = dir ? wb[r] : wf[r];
  ((__hip_bfloat16*)wih)[i] = __float2bfloat16(v);
}

// ---------- scatter source map + packed tags ----------
__global__ __launch_bounds__(256) void k_srcmap(const int* __restrict__ length, const int* __restrict__ cum,
                         const int* __restrict__ tags, int* __restrict__ src, int* __restrict__ ntag){
  const int i = blockIdx.x*256 + threadIdx.x;            // B*N*T = 32768
  const int b = i >> 11, nt = i & 2047, n = nt >> 5, t = nt & 31;
  if (t < length[b*N_ + n]){
    const int dest = cum[b*N_ + n] + t;
    src[b*S_ + dest] = nt;
    ntag[b*S_ + dest] = tags[i];
  }
}

// ---------- build packed new_x (bf16) + mask output ----------
__global__ __launch_bounds__(256) void k_newx(const float* __restrict__ x, const float* __restrict__ gcn,
                      const int* __restrict__ src, const int* __restrict__ doc,
                      ushort* __restrict__ nx, float* __restrict__ mask_out){
  const int r = blockIdx.x; const int b = r >> 11, s = r & 2047;
  const int L = doc[b];
  const int d = threadIdx.x*2;
  const float2 g2 = *(const float2*)&gcn[((size_t)(b*N_ + (s>>5)))*D_ + d];
  float v0 = g2.x, v1 = g2.y;
  if (s < L){
    const int nt = src[r];
    const float2 x2 = *(const float2*)&x[((size_t)(b*S_ + nt))*D_ + d];
    v0 += x2.x; v1 += x2.y;
  }
  __hip_bfloat16* o = (__hip_bfloat16*)nx + (size_t)r*D_ + d;
  o[0] = __float2bfloat16(v0); o[1] = __float2bfloat16(v1);
  if (threadIdx.x == 0) mask_out[r] = (s < L) ? 1.0f : 0.0f;
}

// ---------- input projection GEMM: pre[b][s][dir*1024+g] (f16), bias added ----------
__global__ __launch_bounds__(256) void k_gemm(const ushort* __restrict__ A, const ushort* __restrict__ Bw,
    const float* __restrict__ bias_f, const float* __restrict__ bias_b,
    const int* __restrict__ doc, __half* __restrict__ pre){
  const int m0 = blockIdx.x*128, n0 = blockIdx.y*128;
  const int b = m0 >> 11, s0 = m0 & 2047;
  if (s0 >= doc[b]) return;
  __shared__ __align__(16) ushort la[128*40];
  __shared__ __align__(16) ushort lb[128*40];
  const int tid = threadIdx.x, lane = tid & 63, w = tid >> 6;
  const int wr = w >> 1, wc = w & 1;
  const int fr = lane & 15, fq = lane >> 4;
  f32x4 acc[4][4] = {};
  const int srow = tid >> 1;
  const int sko  = (tid & 1)*16;
  for (int kt = 0; kt < 16; ++kt){
    const int k0 = kt*32;
    const float4 a0 = *(const float4*)&A[(size_t)(m0+srow)*512 + k0 + sko];
    const float4 a1 = *(const float4*)&A[(size_t)(m0+srow)*512 + k0 + sko + 8];
    const float4 b0 = *(const float4*)&Bw[(size_t)(n0+srow)*512 + k0 + sko];
    const float4 b1 = *(const float4*)&Bw[(size_t)(n0+srow)*512 + k0 + sko + 8];
    *(float4*)&la[srow*40 + sko]     = a0;
    *(float4*)&la[srow*40 + sko + 8] = a1;
    *(float4*)&lb[srow*40 + sko]     = b0;
    *(float4*)&lb[srow*40 + sko + 8] = b1;
    __syncthreads();
    s16x8 af[4], bfr[4];
    #pragma unroll
    for (int mi=0; mi<4; ++mi) af[mi] = *(const s16x8*)&la[(wr*64+mi*16+fr)*40 + fq*8];
    #pragma unroll
    for (int ni=0; ni<4; ++ni) bfr[ni] = *(const s16x8*)&lb[(wc*64+ni*16+fr)*40 + fq*8];
    #pragma unroll
    for (int mi=0; mi<4; ++mi){
      #pragma unroll
      for (int ni=0; ni<4; ++ni){
        acc[mi][ni] = __builtin_amdgcn_mfma_f32_16x16x32_bf16(af[mi], bfr[ni], acc[mi][ni], 0, 0, 0);
      }
    }
    __syncthreads();
  }
  #pragma unroll
  for (int ni=0; ni<4; ++ni){
    const int n = n0 + wc*64 + ni*16 + fr;
    const float bv = (n < 1024) ? bias_f[n] : bias_b[n-1024];
    #pragma unroll
    for (int mi=0; mi<4; ++mi){
      const int mb = m0 + wr*64 + mi*16 + fq*4;
      #pragma unroll
      for (int j=0; j<4; ++j)
        pre[(size_t)(mb+j)*2048 + n] = __float2half(acc[mi][ni][j] + bv);
    }
  }
}

// ---------- recurrent LSTM: W_hh resident in VGPRs, 2 CUs per direction ----------
// grid = 4 (dir*2 + half), block = 512 (8 waves; wave wv owns units [wv*16,wv*16+16), all 4 gates)
__global__ __launch_bounds__(512) void k_recur2(
    const float* __restrict__ Wf, const float* __restrict__ Wb,
    const __half* __restrict__ pre, const int* __restrict__ doc,
    unsigned* __restrict__ hx, int* __restrict__ flags,
    float* __restrict__ outh)
{
  const int dir = blockIdx.x >> 1, half = blockIdx.x & 1;
  const int tid = threadIdx.x, lane = tid & 63, wv = tid >> 6;
  const int fr = lane & 15, fq = lane >> 4;
  const float* W = dir ? Wb : Wf;

  __shared__ __align__(16) __half hsm[16*256];   // 8 KB staged h, XOR-swizzled

  int Lmax = 0;
  #pragma unroll
  for (int b = 0; b < 16; ++b) Lmax = max(Lmax, doc[b]);
  int Lv[4];
  #pragma unroll
  for (int j = 0; j < 4; ++j) Lv[j] = doc[fq*4 + j];

  // preload W_hh fragments (f16): lane holds W[row][kt*32+fq*8 .. +8]
  f16x8 wf[32];
  #pragma unroll
  for (int g = 0; g < 4; ++g){
    const int row = g*256 + half*128 + wv*16 + fr;
    #pragma unroll
    for (int kt = 0; kt < 8; ++kt){
      const float4 w0 = *(const float4*)&W[(size_t)row*256 + kt*32 + fq*8];
      const float4 w1 = *(const float4*)&W[(size_t)row*256 + kt*32 + fq*8 + 4];
      union { _Float16 h[8]; f16x8 v; } u;
      u.h[0]=(_Float16)w0.x; u.h[1]=(_Float16)w0.y; u.h[2]=(_Float16)w0.z; u.h[3]=(_Float16)w0.w;
      u.h[4]=(_Float16)w1.x; u.h[5]=(_Float16)w1.y; u.h[6]=(_Float16)w1.z; u.h[7]=(_Float16)w1.w;
      wf[g*8+kt] = u.v;
    }
  }

  const int colbase = dir*1024 + half*128 + wv*16 + fr;   // pre column base (gate 0)
  const int hcol = half*128 + wv*16 + fr;                 // unit index in h
  int* const myflag = &flags[dir*2 + half];
  int* const pflag  = &flags[dir*2 + (1-half)];
  float cst[4] = {0.f,0.f,0.f,0.f};

  for (int t = 0; t < Lmax; ++t){
    // --- prefetch pre-activations for this step (independent of h) ---
    int pos[4]; __half pv[16];
    #pragma unroll
    for (int j = 0; j < 4; ++j){
      const int Lj = Lv[j];
      pos[j] = dir ? max(Lj-1-t, 0) : t;
      const size_t pb = ((size_t)((fq*4+j)*S_ + pos[j]))*2048 + colbase;
      #pragma unroll
      for (int g = 0; g < 4; ++g) pv[j*4+g] = pre[pb + (size_t)g*256];
    }
    // --- wait for partner CU to finish step t-1 ---
    if (t > 0){
      if (tid == 0){
        while (__hip_atomic_load(pflag, __ATOMIC_RELAXED, __HIP_MEMORY_SCOPE_AGENT) < t)
          __builtin_amdgcn_s_sleep(1);
      }
      __syncthreads();
    }
    // --- stage h_{t-1} (coherent atomic loads) into swizzled LDS ---
    {
      const unsigned* hsrc = hx + (size_t)(dir*2 + ((t+1)&1))*2048;
      uint4 hv;
      hv.x = __hip_atomic_load(&hsrc[tid*4+0], __ATOMIC_RELAXED, __HIP_MEMORY_SCOPE_AGENT);
      hv.y = __hip_atomic_load(&hsrc[tid*4+1], __ATOMIC_RELAXED, __HIP_MEMORY_SCOPE_AGENT);
      hv.z = __hip_atomic_load(&hsrc[tid*4+2], __ATOMIC_RELAXED, __HIP_MEMORY_SCOPE_AGENT);
      hv.w = __hip_atomic_load(&hsrc[tid*4+3], __ATOMIC_RELAXED, __HIP_MEMORY_SCOPE_AGENT);
      const int bb = tid >> 5;                       // batch of this 16B block
      const int swb = (tid*16) ^ ((bb & 7) << 4);
      *(uint4*)((char*)hsm + swb) = hv;
    }
    __syncthreads();
    // --- MFMA: gates[batch][unit,gate] ---
    f32x4 acc[4] = {{0,0,0,0},{0,0,0,0},{0,0,0,0},{0,0,0,0}};
    #pragma unroll
    for (int kt = 0; kt < 8; ++kt){
      const int rb = (fr*512 + (kt*32 + fq*8)*2) ^ ((fr & 7) << 4);
      const f16x8 af = *(const f16x8*)((const char*)hsm + rb);
      acc[0] = __builtin_amdgcn_mfma_f32_16x16x32_f16(af, wf[0*8+kt], acc[0], 0,0,0);
      acc[1] = __builtin_amdgcn_mfma_f32_16x16x32_f16(af, wf[1*8+kt], acc[1], 0,0,0);
      acc[2] = __builtin_amdgcn_mfma_f32_16x16x32_f16(af, wf[2*8+kt], acc[2], 0,0,0);
      acc[3] = __builtin_amdgcn_mfma_f32_16x16x32_f16(af, wf[3*8+kt], acc[3], 0,0,0);
    }
    // --- gates + state update + stores (lane holds all 4 gates of its unit) ---
    unsigned* hdst = hx + (size_t)(dir*2 + (t&1))*2048;
    #pragma unroll
    for (int j = 0; j < 4; ++j){
      const int m = fq*4 + j;
      const float gi = acc[0][j] + __half2float(pv[j*4+0]);
      const float gf = acc[1][j] + __half2float(pv[j*4+1]);
      const float gg = acc[2][j] + __half2float(pv[j*4+2]);
      const float go = acc[3][j] + __half2float(pv[j*4+3]);
      const float c = sigm(gf)*cst[j] + sigm(gi)*tanh_fast(gg);
      cst[j] = c;
      const float h = sigm(go)*tanh_fast(c);
      const unsigned my = (unsigned)__half_as_ushort(__float2half(h));
      const unsigned ot = __shfl_xor(my, 1);
      if (!(fr & 1))
        __hip_atomic_store(&hdst[m*128 + (hcol >> 1)], my | (ot << 16),
                           __ATOMIC_RELAXED, __HIP_MEMORY_SCOPE_AGENT);
      if (t < Lv[j])
        outh[((size_t)(m*S_ + pos[j]))*512 + dir*256 + hcol] = h;
    }
    __syncthreads();   // drains all stores (vmcnt0) before flag
    if (tid == 0)
      __hip_atomic_store(myflag, t+1, __ATOMIC_RELAXED, __HIP_MEMORY_SCOPE_AGENT);
  }
}

// ---------- logits: wave per row ----------
__global__ __launch_bounds__(256) void k_logits(const float* __restrict__ outh, const float* __restrict__ mw,
    const float* __restrict__ mb, const int* __restrict__ doc, float* __restrict__ logits){
  const int w = threadIdx.x >> 6, lane = threadIdx.x & 63;
  const int r = blockIdx.x*4 + w;
  const int b = r >> 11, s = r & 2047;
  if (s >= doc[b]){
    if (lane < 13) logits[(size_t)r*13 + lane] = mb[lane];
    return;
  }
  float xv[8];
  #pragma unroll
  for (int m=0; m<8; ++m) xv[m] = outh[(size_t)r*512 + lane + m*64];
  #pragma unroll
  for (int k=0; k<13; ++k){
    float p = 0.f;
    #pragma unroll
    for (int m=0; m<8; ++m) p += xv[m]*mw[k*512 + lane + m*64];
    #pragma unroll
    for (int off=32; off; off>>=1) p += __shfl_down(p, off);
    if (lane == 0) logits[(size_t)r*13 + k] = p + mb[k];
  }
}

// ---------- CRF: one wave per batch ----------
__global__ void k_crf(const float* __restrict__ logits, const int* __restrict__ ntag,
    const int* __restrict__ doc, const float* __restrict__ trans,
    const float* __restrict__ stt, const float* __restrict__ ent, float* __restrict__ ll){
  const int b = blockIdx.x, lane = threadIdx.x;
  const int L = doc[b];
  const float* lg = logits + (size_t)b*S_*13;
  float tc[13];
  #pragma unroll
  for (int i=0; i<13; ++i) tc[i] = (lane < 13) ? trans[i*13 + lane] : 0.f;
  float alpha = (lane < 13) ? (stt[lane] + lg[lane]) : -1e30f;
  for (int t=1; t<L; ++t){
    const float e = (lane < 13) ? lg[(size_t)t*13 + lane] : 0.f;
    float v[13]; float m = -1e30f;
    #pragma unroll
    for (int i=0; i<13; ++i){ v[i] = __shfl(alpha, i) + tc[i]; m = fmaxf(m, v[i]); }
    float sum = 0.f;
    #pragma unroll
    for (int i=0; i<13; ++i) sum += __expf(v[i] - m);
    alpha = m + __logf(sum) + e;
  }
  float av = (lane < 13) ? alpha + ent[lane] : -1e30f;
  float m2 = -1e30f;
  #pragma unroll
  for (int i=0; i<13; ++i) m2 = fmaxf(m2, __shfl(av, i));
  float s2 = 0.f;
  #pragma unroll
  for (int i=0; i<13; ++i) s2 += __expf(__shfl(av, i) - m2);
  const float logz = m2 + __logf(s2);
  const int* tg = ntag + (size_t)b*S_;
  float num = 0.f;
  for (int t = lane; t < L; t += 64){
    const int cur = tg[t];
    num += lg[(size_t)t*13 + cur];
    if (t >= 1) num += trans[tg[t-1]*13 + cur];
  }
  #pragma unroll
  for (int off=32; off; off>>=1) num += __shfl_down(num, off);
  if (lane == 0){
    num += stt[tg[0]] + ent[tg[L-1]];
    ll[b] = num - logz;
  }
}

extern "C" void kernel_launch(void* const* d_in, const int* in_sizes, int n_in,
                              void* d_out, int out_size, void* d_ws, size_t ws_size,
                              hipStream_t stream){
  const float* x    = (const float*)d_in[0];
  const float* gcn  = (const float*)d_in[1];
  const int* length = (const int*)d_in[3];
  const int* tags   = (const int*)d_in[4];
  const float* wihf = (const float*)d_in[5];
  const float* whhf = (const float*)d_in[6];
  const float* bf   = (const float*)d_in[7];
  const float* wihb = (const float*)d_in[8];
  const float* whhb = (const float*)d_in[9];
  const float* bb   = (const float*)d_in[10];
  const float* mw   = (const float*)d_in[11];
  const float* mb   = (const float*)d_in[12];
  const float* trans= (const float*)d_in[13];
  const float* stt  = (const float*)d_in[14];
  const float* ent  = (const float*)d_in[15];

  char* ws = (char*)d_ws;
  ushort* nx   = (ushort*)(ws + 0);              // 33,554,432 B  new_x bf16
  __half* pre  = (__half*)(ws + 33554432);       // 134,217,728 B pre-activations f16
  float*  outh = (float*)(ws + 167772160);       // 67,108,864 B  concat h states
  ushort* wih  = (ushort*)(ws + 234881024);      // 2,097,152 B   w_ih bf16 [2048][512]
  int*    src  = (int*)(ws + 238026752);         // 131,072 B (reused after k_newx: hx+flags)
  int*    ntag = (int*)(ws + 238157824);         // 131,072 B
  int*    cum  = (int*)(ws + 238288896);         // 4,096 B
  int*    doc  = (int*)(ws + 238292992);         // 64 B

  unsigned* hx    = (unsigned*)(ws + 238026752); // 32,768 B (overlaps dead src buffer)
  int*      flags = (int*)(ws + 238026752 + 32768); // 16 B

  float* logits  = (float*)d_out;                // 425,984 floats
  float* maskout = logits + 425984;              // 32,768 floats
  float* ll      = maskout + 32768;              // 16 floats

  hipLaunchKernelGGL(k_prep,   dim3(1),        dim3(1024), 0, stream, length, cum, doc);
  hipLaunchKernelGGL(k_cast,   dim3(4096),     dim3(256),  0, stream, wihf, wihb, wih);
  hipLaunchKernelGGL(k_srcmap, dim3(128),      dim3(256),  0, stream, length, cum, tags, src, ntag);
  hipLaunchKernelGGL(k_newx,   dim3(32768),    dim3(256),  0, stream, x, gcn, src, doc, nx, maskout);
  // src is dead from here on: reuse its space for h-exchange + step flags (must be zeroed each launch)
  hipMemsetAsync(ws + 238026752, 0, 32768 + 16, stream);
  hipLaunchKernelGGL(k_gemm,   dim3(256, 16),  dim3(256),  0, stream, nx, wih, bf, bb, doc, pre);
  hipLaunchKernelGGL(k_recur2, dim3(4),        dim3(512),  0, stream, whhf, whhb, pre, doc, hx, flags, outh);
  hipLaunchKernelGGL(k_logits, dim3(8192),     dim3(256),  0, stream, outh, mw, mb, doc, logits);
  hipLaunchKernelGGL(k_crf,    dim3(16),       dim3(64),   0, stream, logits, ntag, doc, trans, stt, ent, ll);
}

// Round 3
// 3901.383 us; speedup vs baseline: 1.3907x; 1.2309x over previous
//
#include <hip/hip_runtime.h>
#include <hip/hip_fp16.h>
#include <hip/hip_bf16.h>

#define B_ 16
#define N_ 64
#define T_ 32
#define D_ 512
#define H_ 256
#define K_ 13
#define S_ 2048
#define G4_ 1024

typedef float f32x4 __attribute__((ext_vector_type(4)));
typedef short s16x8 __attribute__((ext_vector_type(8)));
typedef int   i32x4 __attribute__((ext_vector_type(4)));

#define INVQ 2.0505324e-5f   /* 1/(384*127) */

__device__ __forceinline__ float sigm(float x){ return 1.0f/(1.0f+__expf(-x)); }
__device__ __forceinline__ float tanh_fast(float x){ return 1.0f - 2.0f/(1.0f+__expf(2.0f*x)); }

// ---------- prefix sums over segment lengths ----------
__global__ void k_prep(const int* __restrict__ length, int* __restrict__ cum, int* __restrict__ doc){
  const int b = threadIdx.x >> 6, n = threadIdx.x & 63;
  const int v = length[b*N_ + n];
  int x = v;
  #pragma unroll
  for (int d = 1; d < 64; d <<= 1){
    int y = __shfl_up(x, d);
    if (n >= d) x += y;
  }
  cum[b*N_ + n] = x - v;          // exclusive
  if (n == 63) doc[b] = x;        // doc_len
}

// ---------- cast weights: w_ih -> bf16 [2048][512]; w_hh -> i8 [dir][1024][256] ----------
__global__ __launch_bounds__(256) void k_cast(const float* __restrict__ wf, const float* __restrict__ wb,
                       const float* __restrict__ hf, const float* __restrict__ hb,
                       ushort* __restrict__ wih, signed char* __restrict__ whh8){
  const int i = blockIdx.x*256 + threadIdx.x;
  if (i < 2*G4_*D_){
    const int dir = i / (G4_*D_); const int r = i % (G4_*D_);
    const float v = dir ? wb[r] : wf[r];
    ((__hip_bfloat16*)wih)[i] = __float2bfloat16(v);
  } else {
    const int j2 = i - 2*G4_*D_;
    if (j2 < 2*G4_*H_){
      const int dir = j2 >> 18; const int r = j2 & 262143;
      const float v = (dir ? hb : hf)[r];
      int q = (int)rintf(v * 384.0f);
      whh8[j2] = (signed char)min(127, max(-127, q));
    }
  }
}

// ---------- scatter source map + packed tags ----------
__global__ __launch_bounds__(256) void k_srcmap(const int* __restrict__ length, const int* __restrict__ cum,
                         const int* __restrict__ tags, int* __restrict__ src, int* __restrict__ ntag){
  const int i = blockIdx.x*256 + threadIdx.x;            // B*N*T = 32768
  const int b = i >> 11, nt = i & 2047, n = nt >> 5, t = nt & 31;
  if (t < length[b*N_ + n]){
    const int dest = cum[b*N_ + n] + t;
    src[b*S_ + dest] = nt;
    ntag[b*S_ + dest] = tags[i];
  }
}

// ---------- build packed new_x (bf16) + mask output ----------
__global__ __launch_bounds__(256) void k_newx(const float* __restrict__ x, const float* __restrict__ gcn,
                      const int* __restrict__ src, const int* __restrict__ doc,
                      ushort* __restrict__ nx, float* __restrict__ mask_out){
  const int r = blockIdx.x; const int b = r >> 11, s = r & 2047;
  const int L = doc[b];
  const int d = threadIdx.x*2;
  const float2 g2 = *(const float2*)&gcn[((size_t)(b*N_ + (s>>5)))*D_ + d];
  float v0 = g2.x, v1 = g2.y;
  if (s < L){
    const int nt = src[r];
    const float2 x2 = *(const float2*)&x[((size_t)(b*S_ + nt))*D_ + d];
    v0 += x2.x; v1 += x2.y;
  }
  __hip_bfloat16* o = (__hip_bfloat16*)nx + (size_t)r*D_ + d;
  o[0] = __float2bfloat16(v0); o[1] = __float2bfloat16(v1);
  if (threadIdx.x == 0) mask_out[r] = (s < L) ? 1.0f : 0.0f;
}

// ---------- input projection GEMM: pre[b][s][dir*1024+g*256+u] (f16), bias added ----------
__global__ __launch_bounds__(256) void k_gemm(const ushort* __restrict__ A, const ushort* __restrict__ Bw,
    const float* __restrict__ bias_f, const float* __restrict__ bias_b,
    const int* __restrict__ doc, __half* __restrict__ pre){
  const int m0 = blockIdx.x*128, n0 = blockIdx.y*128;
  const int b = m0 >> 11, s0 = m0 & 2047;
  if (s0 >= doc[b]) return;
  __shared__ __align__(16) ushort la[128*40];
  __shared__ __align__(16) ushort lb[128*40];
  const int tid = threadIdx.x, lane = tid & 63, w = tid >> 6;
  const int wr = w >> 1, wc = w & 1;
  const int fr = lane & 15, fq = lane >> 4;
  f32x4 acc[4][4] = {};
  const int srow = tid >> 1;
  const int sko  = (tid & 1)*16;
  for (int kt = 0; kt < 16; ++kt){
    const int k0 = kt*32;
    const float4 a0 = *(const float4*)&A[(size_t)(m0+srow)*512 + k0 + sko];
    const float4 a1 = *(const float4*)&A[(size_t)(m0+srow)*512 + k0 + sko + 8];
    const float4 b0 = *(const float4*)&Bw[(size_t)(n0+srow)*512 + k0 + sko];
    const float4 b1 = *(const float4*)&Bw[(size_t)(n0+srow)*512 + k0 + sko + 8];
    *(float4*)&la[srow*40 + sko]     = a0;
    *(float4*)&la[srow*40 + sko + 8] = a1;
    *(float4*)&lb[srow*40 + sko]     = b0;
    *(float4*)&lb[srow*40 + sko + 8] = b1;
    __syncthreads();
    s16x8 af[4], bfr[4];
    #pragma unroll
    for (int mi=0; mi<4; ++mi) af[mi] = *(const s16x8*)&la[(wr*64+mi*16+fr)*40 + fq*8];
    #pragma unroll
    for (int ni=0; ni<4; ++ni) bfr[ni] = *(const s16x8*)&lb[(wc*64+ni*16+fr)*40 + fq*8];
    #pragma unroll
    for (int mi=0; mi<4; ++mi){
      #pragma unroll
      for (int ni=0; ni<4; ++ni){
        acc[mi][ni] = __builtin_amdgcn_mfma_f32_16x16x32_bf16(af[mi], bfr[ni], acc[mi][ni], 0, 0, 0);
      }
    }
    __syncthreads();
  }
  #pragma unroll
  for (int ni=0; ni<4; ++ni){
    const int n = n0 + wc*64 + ni*16 + fr;
    const float bv = (n < 1024) ? bias_f[n] : bias_b[n-1024];
    #pragma unroll
    for (int mi=0; mi<4; ++mi){
      const int mb = m0 + wr*64 + mi*16 + fq*4;
      #pragma unroll
      for (int j=0; j<4; ++j)
        pre[(size_t)(mb+j)*2048 + n] = __float2half(acc[mi][ni][j] + bv);
    }
  }
}

// ---------- recurrent LSTM: i8 W_hh resident in VGPRs, batch-split, NO inter-block sync ----------
// grid = 4: blockIdx = dir*2 + batch-half. 512 threads = 8 waves; wave wv owns units [wv*32, wv*32+32).
__global__ __launch_bounds__(512) void k_recur3(
    const signed char* __restrict__ W8,
    const __half* __restrict__ pre, const int* __restrict__ doc,
    float* __restrict__ outh)
{
  const int dir = blockIdx.x >> 1, bh = blockIdx.x & 1;
  const int tid = threadIdx.x, lane = tid & 63, wv = tid >> 6;
  const int fr = lane & 15, fq = lane >> 4;

  __shared__ __align__(16) unsigned char hsm[2][16][288];   // i8 h, dbuf, padded rows
  for (int i = tid; i < 2304; i += 512) ((unsigned*)hsm)[i] = 0u;

  int Lv[4]; int Lblk = 0;
  #pragma unroll
  for (int j = 0; j < 4; ++j) Lv[j] = doc[bh*8 + (fq&1)*4 + j];
  #pragma unroll
  for (int b = 0; b < 8; ++b) Lblk = max(Lblk, doc[bh*8 + b]);

  // preload W_hh i8 fragments: B-frag lane holds W[row=g*256+u_tile][k = kt*64 + fq*16 .. +15]
  i32x4 wfrag[2][4][4];
  #pragma unroll
  for (int nt = 0; nt < 2; ++nt)
    #pragma unroll
    for (int g = 0; g < 4; ++g){
      const int row = g*256 + wv*32 + nt*16 + fr;
      #pragma unroll
      for (int kt = 0; kt < 4; ++kt)
        wfrag[nt][g][kt] = *(const i32x4*)&W8[(size_t)dir*262144 + (size_t)row*256 + kt*64 + fq*16];
    }

  const int u = wv*32 + (fq>>1)*16 + fr;   // unit this thread owns in the gate phase
  const int bloc = (fq&1)*4;               // first local batch of this thread
  float cst[4] = {0.f,0.f,0.f,0.f};
  __half pva[16], pvb[16];

  auto fetch = [&](int tt, __half (&dst)[16]){
    #pragma unroll
    for (int j = 0; j < 4; ++j){
      const int gb = bh*8 + bloc + j;
      const int pos = dir ? max(Lv[j]-1-tt, 0) : tt;
      const __half* p = pre + ((size_t)(gb*S_ + pos))*2048 + dir*1024 + u;
      #pragma unroll
      for (int g = 0; g < 4; ++g) dst[j*4+g] = p[(size_t)g*256];
    }
  };

  __syncthreads();
  fetch(0, pva);

  auto stepbody = [&](int t, __half (&cur)[16], __half (&nxt)[16]){
    if (t+1 < Lblk) fetch(t+1, nxt);     // prefetch next step (latency hidden)
    const int rbuf = (t+1)&1, wbuf = t&1;
    i32x4 acc[2][4] = {};
    #pragma unroll
    for (int kt = 0; kt < 4; ++kt){
      const i32x4 af = *(const i32x4*)&hsm[rbuf][fr][kt*64 + fq*16];
      #pragma unroll
      for (int nt = 0; nt < 2; ++nt)
        #pragma unroll
        for (int g = 0; g < 4; ++g)
          acc[nt][g] = __builtin_amdgcn_mfma_i32_16x16x64_i8(af, wfrag[nt][g][kt], acc[nt][g], 0, 0, 0);
    }
    // redistribute: lanes fq>=2 take nt=1 rows from lane^32; each thread then owns 4 live states
    float hs[4];
    #pragma unroll
    for (int j = 0; j < 4; ++j){
      float gv[4];
      #pragma unroll
      for (int g = 0; g < 4; ++g){
        const int sw = __shfl_xor(acc[1][g][j], 32);
        const int ai = (fq < 2) ? acc[0][g][j] : sw;
        gv[g] = (float)ai * INVQ + __half2float(cur[j*4+g]);
      }
      const float c = sigm(gv[1])*cst[j] + sigm(gv[0])*tanh_fast(gv[2]);
      cst[j] = c;
      hs[j] = sigm(gv[3])*tanh_fast(c);
    }
    // quantize h -> i8, pack 4 bytes across fr&3 group, write LDS; store outh
    #pragma unroll
    for (int j = 0; j < 4; ++j){
      int q = (int)rintf(hs[j]*127.0f);
      q = min(127, max(-127, q));
      unsigned v = ((unsigned)(q & 255)) << ((fr & 3)*8);
      v |= __shfl_xor(v, 1);
      v |= __shfl_xor(v, 2);
      if ((fr & 3) == 0)
        *(unsigned*)&hsm[wbuf][bloc + j][u & ~3] = v;
      if (t < Lv[j])
        outh[((size_t)((bh*8 + bloc + j)*S_ + (dir ? (Lv[j]-1-t) : t)))*512 + dir*256 + u] = hs[j];
    }
    __syncthreads();
  };

  for (int t = 0; t < Lblk; t += 2){
    stepbody(t, pva, pvb);
    if (t+1 < Lblk) stepbody(t+1, pvb, pva);
  }
}

// ---------- logits: wave per row ----------
__global__ __launch_bounds__(256) void k_logits(const float* __restrict__ outh, const float* __restrict__ mw,
    const float* __restrict__ mb, const int* __restrict__ doc, float* __restrict__ logits){
  const int w = threadIdx.x >> 6, lane = threadIdx.x & 63;
  const int r = blockIdx.x*4 + w;
  const int b = r >> 11, s = r & 2047;
  if (s >= doc[b]){
    if (lane < 13) logits[(size_t)r*13 + lane] = mb[lane];
    return;
  }
  float xv[8];
  #pragma unroll
  for (int m=0; m<8; ++m) xv[m] = outh[(size_t)r*512 + lane + m*64];
  #pragma unroll
  for (int k=0; k<13; ++k){
    float p = 0.f;
    #pragma unroll
    for (int m=0; m<8; ++m) p += xv[m]*mw[k*512 + lane + m*64];
    #pragma unroll
    for (int off=32; off; off>>=1) p += __shfl_down(p, off);
    if (lane == 0) logits[(size_t)r*13 + k] = p + mb[k];
  }
}

// ---------- CRF: one wave per batch ----------
__global__ void k_crf(const float* __restrict__ logits, const int* __restrict__ ntag,
    const int* __restrict__ doc, const float* __restrict__ trans,
    const float* __restrict__ stt, const float* __restrict__ ent, float* __restrict__ ll){
  const int b = blockIdx.x, lane = threadIdx.x;
  const int L = doc[b];
  const float* lg = logits + (size_t)b*S_*13;
  float tc[13];
  #pragma unroll
  for (int i=0; i<13; ++i) tc[i] = (lane < 13) ? trans[i*13 + lane] : 0.f;
  float alpha = (lane < 13) ? (stt[lane] + lg[lane]) : -1e30f;
  for (int t=1; t<L; ++t){
    const float e = (lane < 13) ? lg[(size_t)t*13 + lane] : 0.f;
    float v[13]; float m = -1e30f;
    #pragma unroll
    for (int i=0; i<13; ++i){ v[i] = __shfl(alpha, i) + tc[i]; m = fmaxf(m, v[i]); }
    float sum = 0.f;
    #pragma unroll
    for (int i=0; i<13; ++i) sum += __expf(v[i] - m);
    alpha = m + __logf(sum) + e;
  }
  float av = (lane < 13) ? alpha + ent[lane] : -1e30f;
  float m2 = -1e30f;
  #pragma unroll
  for (int i=0; i<13; ++i) m2 = fmaxf(m2, __shfl(av, i));
  float s2 = 0.f;
  #pragma unroll
  for (int i=0; i<13; ++i) s2 += __expf(__shfl(av, i) - m2);
  const float logz = m2 + __logf(s2);
  const int* tg = ntag + (size_t)b*S_;
  float num = 0.f;
  for (int t = lane; t < L; t += 64){
    const int cur = tg[t];
    num += lg[(size_t)t*13 + cur];
    if (t >= 1) num += trans[tg[t-1]*13 + cur];
  }
  #pragma unroll
  for (int off=32; off; off>>=1) num += __shfl_down(num, off);
  if (lane == 0){
    num += stt[tg[0]] + ent[tg[L-1]];
    ll[b] = num - logz;
  }
}

extern "C" void kernel_launch(void* const* d_in, const int* in_sizes, int n_in,
                              void* d_out, int out_size, void* d_ws, size_t ws_size,
                              hipStream_t stream){
  const float* x    = (const float*)d_in[0];
  const float* gcn  = (const float*)d_in[1];
  const int* length = (const int*)d_in[3];
  const int* tags   = (const int*)d_in[4];
  const float* wihf = (const float*)d_in[5];
  const float* whhf = (const float*)d_in[6];
  const float* bf   = (const float*)d_in[7];
  const float* wihb = (const float*)d_in[8];
  const float* whhb = (const float*)d_in[9];
  const float* bb   = (const float*)d_in[10];
  const float* mw   = (const float*)d_in[11];
  const float* mb   = (const float*)d_in[12];
  const float* trans= (const float*)d_in[13];
  const float* stt  = (const float*)d_in[14];
  const float* ent  = (const float*)d_in[15];

  char* ws = (char*)d_ws;
  ushort* nx   = (ushort*)(ws + 0);              // 33,554,432 B  new_x bf16
  __half* pre  = (__half*)(ws + 33554432);       // 134,217,728 B pre-activations f16
  float*  outh = (float*)(ws + 167772160);       // 67,108,864 B  concat h states
  ushort* wih  = (ushort*)(ws + 234881024);      // 2,097,152 B   w_ih bf16 [2048][512]
  signed char* whh8 = (signed char*)(ws + 236978176); // 524,288 B w_hh i8 [2][1024][256]
  int*    src  = (int*)(ws + 238026752);         // 131,072 B
  int*    ntag = (int*)(ws + 238157824);         // 131,072 B
  int*    cum  = (int*)(ws + 238288896);         // 4,096 B
  int*    doc  = (int*)(ws + 238292992);         // 64 B

  float* logits  = (float*)d_out;                // 425,984 floats
  float* maskout = logits + 425984;              // 32,768 floats
  float* ll      = maskout + 32768;              // 16 floats

  hipLaunchKernelGGL(k_prep,   dim3(1),        dim3(1024), 0, stream, length, cum, doc);
  hipLaunchKernelGGL(k_cast,   dim3(6144),     dim3(256),  0, stream, wihf, wihb, whhf, whhb, wih, whh8);
  hipLaunchKernelGGL(k_srcmap, dim3(128),      dim3(256),  0, stream, length, cum, tags, src, ntag);
  hipLaunchKernelGGL(k_newx,   dim3(32768),    dim3(256),  0, stream, x, gcn, src, doc, nx, maskout);
  hipLaunchKernelGGL(k_gemm,   dim3(256, 16),  dim3(256),  0, stream, nx, wih, bf, bb, doc, pre);
  hipLaunchKernelGGL(k_recur3, dim3(4),        dim3(512),  0, stream, whh8, pre, doc, outh);
  hipLaunchKernelGGL(k_logits, dim3(8192),     dim3(256),  0, stream, outh, mw, mb, doc, logits);
  hipLaunchKernelGGL(k_crf,    dim3(16),       dim3(64),   0, stream, logits, ntag, doc, trans, stt, ent, ll);
}

// Round 4
// 1891.862 us; speedup vs baseline: 2.8680x; 2.0622x over previous
//
#include <hip/hip_runtime.h>
#include <hip/hip_fp16.h>
#include <hip/hip_bf16.h>

#define B_ 16
#define N_ 64
#define T_ 32
#define D_ 512
#define H_ 256
#define K_ 13
#define S_ 2048
#define G4_ 1024

typedef float f32x4 __attribute__((ext_vector_type(4)));
typedef short s16x8 __attribute__((ext_vector_type(8)));
typedef int   i32x4 __attribute__((ext_vector_type(4)));

#define INVQ 2.0505324e-5f   /* 1/(384*127) */

// barrier with LDS-only drain: do NOT wait vmcnt (prefetch loads / outh stores stay in flight)
#define BAR() do { \
  asm volatile("s_waitcnt lgkmcnt(0)" ::: "memory"); \
  __builtin_amdgcn_s_barrier(); \
  __builtin_amdgcn_sched_barrier(0); \
} while (0)

__device__ __forceinline__ float sigm(float x){ return 1.0f/(1.0f+__expf(-x)); }
__device__ __forceinline__ float tanh_fast(float x){ return 1.0f - 2.0f/(1.0f+__expf(2.0f*x)); }

// ---------- prefix sums over segment lengths ----------
__global__ void k_prep(const int* __restrict__ length, int* __restrict__ cum, int* __restrict__ doc){
  const int b = threadIdx.x >> 6, n = threadIdx.x & 63;
  const int v = length[b*N_ + n];
  int x = v;
  #pragma unroll
  for (int d = 1; d < 64; d <<= 1){
    int y = __shfl_up(x, d);
    if (n >= d) x += y;
  }
  cum[b*N_ + n] = x - v;          // exclusive
  if (n == 63) doc[b] = x;        // doc_len
}

// ---------- cast weights: w_ih -> bf16 [2048][512]; w_hh -> i8 [dir][1024][256] ----------
__global__ __launch_bounds__(256) void k_cast(const float* __restrict__ wf, const float* __restrict__ wb,
                       const float* __restrict__ hf, const float* __restrict__ hb,
                       ushort* __restrict__ wih, signed char* __restrict__ whh8){
  const int i = blockIdx.x*256 + threadIdx.x;
  if (i < 2*G4_*D_){
    const int dir = i / (G4_*D_); const int r = i % (G4_*D_);
    const float v = dir ? wb[r] : wf[r];
    ((__hip_bfloat16*)wih)[i] = __float2bfloat16(v);
  } else {
    const int j2 = i - 2*G4_*D_;
    if (j2 < 2*G4_*H_){
      const int dir = j2 >> 18; const int r = j2 & 262143;
      const float v = (dir ? hb : hf)[r];
      int q = (int)rintf(v * 384.0f);
      whh8[j2] = (signed char)min(127, max(-127, q));
    }
  }
}

// ---------- scatter source map + packed tags ----------
__global__ __launch_bounds__(256) void k_srcmap(const int* __restrict__ length, const int* __restrict__ cum,
                         const int* __restrict__ tags, int* __restrict__ src, int* __restrict__ ntag){
  const int i = blockIdx.x*256 + threadIdx.x;            // B*N*T = 32768
  const int b = i >> 11, nt = i & 2047, n = nt >> 5, t = nt & 31;
  if (t < length[b*N_ + n]){
    const int dest = cum[b*N_ + n] + t;
    src[b*S_ + dest] = nt;
    ntag[b*S_ + dest] = tags[i];
  }
}

// ---------- build packed new_x (bf16) + mask output ----------
__global__ __launch_bounds__(256) void k_newx(const float* __restrict__ x, const float* __restrict__ gcn,
                      const int* __restrict__ src, const int* __restrict__ doc,
                      ushort* __restrict__ nx, float* __restrict__ mask_out){
  const int r = blockIdx.x; const int b = r >> 11, s = r & 2047;
  const int L = doc[b];
  const int d = threadIdx.x*2;
  const float2 g2 = *(const float2*)&gcn[((size_t)(b*N_ + (s>>5)))*D_ + d];
  float v0 = g2.x, v1 = g2.y;
  if (s < L){
    const int nt = src[r];
    const float2 x2 = *(const float2*)&x[((size_t)(b*S_ + nt))*D_ + d];
    v0 += x2.x; v1 += x2.y;
  }
  __hip_bfloat16* o = (__hip_bfloat16*)nx + (size_t)r*D_ + d;
  o[0] = __float2bfloat16(v0); o[1] = __float2bfloat16(v1);
  if (threadIdx.x == 0) mask_out[r] = (s < L) ? 1.0f : 0.0f;
}

// ---------- input projection GEMM: pre[b][s][dir*1024+g*256+u] (f16), bias added ----------
__global__ __launch_bounds__(256) void k_gemm(const ushort* __restrict__ A, const ushort* __restrict__ Bw,
    const float* __restrict__ bias_f, const float* __restrict__ bias_b,
    const int* __restrict__ doc, __half* __restrict__ pre){
  const int m0 = blockIdx.x*128, n0 = blockIdx.y*128;
  const int b = m0 >> 11, s0 = m0 & 2047;
  if (s0 >= doc[b]) return;
  __shared__ __align__(16) ushort la[128*40];
  __shared__ __align__(16) ushort lb[128*40];
  const int tid = threadIdx.x, lane = tid & 63, w = tid >> 6;
  const int wr = w >> 1, wc = w & 1;
  const int fr = lane & 15, fq = lane >> 4;
  f32x4 acc[4][4] = {};
  const int srow = tid >> 1;
  const int sko  = (tid & 1)*16;
  for (int kt = 0; kt < 16; ++kt){
    const int k0 = kt*32;
    const float4 a0 = *(const float4*)&A[(size_t)(m0+srow)*512 + k0 + sko];
    const float4 a1 = *(const float4*)&A[(size_t)(m0+srow)*512 + k0 + sko + 8];
    const float4 b0 = *(const float4*)&Bw[(size_t)(n0+srow)*512 + k0 + sko];
    const float4 b1 = *(const float4*)&Bw[(size_t)(n0+srow)*512 + k0 + sko + 8];
    *(float4*)&la[srow*40 + sko]     = a0;
    *(float4*)&la[srow*40 + sko + 8] = a1;
    *(float4*)&lb[srow*40 + sko]     = b0;
    *(float4*)&lb[srow*40 + sko + 8] = b1;
    __syncthreads();
    s16x8 af[4], bfr[4];
    #pragma unroll
    for (int mi=0; mi<4; ++mi) af[mi] = *(const s16x8*)&la[(wr*64+mi*16+fr)*40 + fq*8];
    #pragma unroll
    for (int ni=0; ni<4; ++ni) bfr[ni] = *(const s16x8*)&lb[(wc*64+ni*16+fr)*40 + fq*8];
    #pragma unroll
    for (int mi=0; mi<4; ++mi){
      #pragma unroll
      for (int ni=0; ni<4; ++ni){
        acc[mi][ni] = __builtin_amdgcn_mfma_f32_16x16x32_bf16(af[mi], bfr[ni], acc[mi][ni], 0, 0, 0);
      }
    }
    __syncthreads();
  }
  #pragma unroll
  for (int ni=0; ni<4; ++ni){
    const int n = n0 + wc*64 + ni*16 + fr;
    const float bv = (n < 1024) ? bias_f[n] : bias_b[n-1024];
    #pragma unroll
    for (int mi=0; mi<4; ++mi){
      const int mb = m0 + wr*64 + mi*16 + fq*4;
      #pragma unroll
      for (int j=0; j<4; ++j)
        pre[(size_t)(mb+j)*2048 + n] = __float2half(acc[mi][ni][j] + bv);
    }
  }
}

// ---------- recurrent LSTM: one block per (batch,dir) chain; i8 W_hh in VGPRs ----------
// grid = 32: blockIdx = b*2 + dir. 512 threads = 8 waves; wave wv owns units [wv*32, wv*32+32) x 4 gates.
__global__ __launch_bounds__(512, 2) void k_recur4(
    const signed char* __restrict__ W8,
    const __half* __restrict__ pre, const int* __restrict__ doc,
    float* __restrict__ outh)
{
  const int b = blockIdx.x >> 1, dir = blockIdx.x & 1;
  const int tid = threadIdx.x, lane = tid & 63, wv = tid >> 6;
  const int L = doc[b];

  __shared__ __align__(16) unsigned char hq[2][256];   // i8 h, double-buffered
  __shared__ __align__(16) __half pls[2][1024];        // staged pre rows, double-buffered

  if (tid < 128) ((unsigned*)hq)[tid] = 0u;

  // preload W_hh i8 B-fragments: lane holds W[row=g*256+wv*32+nt*16+(lane&15)][kt*64+(lane>>4)*16 ..+16]
  i32x4 wfrag[2][4][4];
  #pragma unroll
  for (int nt = 0; nt < 2; ++nt)
    #pragma unroll
    for (int g = 0; g < 4; ++g){
      const int row = g*256 + wv*32 + nt*16 + (lane & 15);
      #pragma unroll
      for (int kt = 0; kt < 4; ++kt)
        wfrag[nt][g][kt] = *(const i32x4*)&W8[(size_t)dir*262144 + (size_t)row*256 + kt*64 + (lane>>4)*16];
    }

  auto ldpre = [&](int tt){
    const int pos = dir ? max(L-1-tt, 0) : tt;
    return *(const unsigned*)(pre + ((size_t)(b*S_ + pos))*2048 + dir*1024 + tid*2);
  };

  // prologue: stage pre(0); keep pre(1), pre(2) in flight (distance-3 pipeline)
  const unsigned s0v = ldpre(0);
  unsigned f1 = (1 < L) ? ldpre(1) : 0u;
  unsigned f2 = (2 < L) ? ldpre(2) : 0u;
  *(unsigned*)((char*)&pls[0][0] + tid*4) = s0v;
  BAR();

  float cst = 0.f;                       // c state (lanes 0..31)
  const int u = wv*32 + (lane & 31);     // unit owned in gate phase
  for (int t = 0; t < L; ++t){
    const int pcur = t & 1, pnxt = pcur ^ 1;
    const int rbuf = (t+1) & 1, wbuf = t & 1;
    const unsigned rn = (t+3 < L) ? ldpre(t+3) : 0u;

    // A-fragments: only lanes with (lane&15)==0 carry live h rows; others stay zero
    i32x4 af[4] = {{0,0,0,0},{0,0,0,0},{0,0,0,0},{0,0,0,0}};
    if ((lane & 15) == 0){
      #pragma unroll
      for (int kt = 0; kt < 4; ++kt)
        af[kt] = *(const i32x4*)&hq[rbuf][kt*64 + (lane >> 4)*16];
    }
    i32x4 acc[2][4] = {};
    #pragma unroll
    for (int kt = 0; kt < 4; ++kt)
      #pragma unroll
      for (int nt = 0; nt < 2; ++nt)
        #pragma unroll
        for (int g = 0; g < 4; ++g)
          acc[nt][g] = __builtin_amdgcn_mfma_i32_16x16x64_i8(af[kt], wfrag[nt][g][kt], acc[nt][g], 0, 0, 0);

    // live gates: row 0 = lanes 0-15 (tile nt), spread nt=1 to lanes 16-31
    int ac[4];
    #pragma unroll
    for (int g = 0; g < 4; ++g){
      const int sw = __shfl_xor(acc[1][g][0], 16);
      ac[g] = (lane < 16) ? acc[0][g][0] : sw;
    }
    float hval = 0.f;
    const int pos = dir ? (L-1-t) : t;
    if (lane < 32){
      float gv[4];
      #pragma unroll
      for (int g = 0; g < 4; ++g)
        gv[g] = (float)ac[g]*INVQ + __half2float(pls[pcur][g*256 + u]);
      const float c = sigm(gv[1])*cst + sigm(gv[0])*tanh_fast(gv[2]);
      cst = c;
      hval = sigm(gv[3])*tanh_fast(c);
      outh[((size_t)(b*S_ + pos))*512 + dir*256 + u] = hval;
    }
    // quantize + pack 4 lanes -> dword, write next h buffer
    int q = (int)rintf(hval*127.0f);
    q = min(127, max(-127, q));
    unsigned v = ((unsigned)(q & 255)) << ((lane & 3)*8);
    v |= __shfl_xor(v, 1);
    v |= __shfl_xor(v, 2);
    if (lane < 32 && (lane & 3) == 0)
      *(unsigned*)&hq[wbuf][u & ~3] = v;
    // stage pre(t+1) for next step
    if (t+1 < L)
      *(unsigned*)((char*)&pls[pnxt][0] + tid*4) = f1;
    f1 = f2; f2 = rn;
    BAR();
  }
}

// ---------- logits: wave per row ----------
__global__ __launch_bounds__(256) void k_logits(const float* __restrict__ outh, const float* __restrict__ mw,
    const float* __restrict__ mb, const int* __restrict__ doc, float* __restrict__ logits){
  const int w = threadIdx.x >> 6, lane = threadIdx.x & 63;
  const int r = blockIdx.x*4 + w;
  const int b = r >> 11, s = r & 2047;
  if (s >= doc[b]){
    if (lane < 13) logits[(size_t)r*13 + lane] = mb[lane];
    return;
  }
  float xv[8];
  #pragma unroll
  for (int m=0; m<8; ++m) xv[m] = outh[(size_t)r*512 + lane + m*64];
  #pragma unroll
  for (int k=0; k<13; ++k){
    float p = 0.f;
    #pragma unroll
    for (int m=0; m<8; ++m) p += xv[m]*mw[k*512 + lane + m*64];
    #pragma unroll
    for (int off=32; off; off>>=1) p += __shfl_down(p, off);
    if (lane == 0) logits[(size_t)r*13 + k] = p + mb[k];
  }
}

// ---------- CRF: one wave per batch ----------
__global__ void k_crf(const float* __restrict__ logits, const int* __restrict__ ntag,
    const int* __restrict__ doc, const float* __restrict__ trans,
    const float* __restrict__ stt, const float* __restrict__ ent, float* __restrict__ ll){
  const int b = blockIdx.x, lane = threadIdx.x;
  const int L = doc[b];
  const float* lg = logits + (size_t)b*S_*13;
  float tc[13];
  #pragma unroll
  for (int i=0; i<13; ++i) tc[i] = (lane < 13) ? trans[i*13 + lane] : 0.f;
  float alpha = (lane < 13) ? (stt[lane] + lg[lane]) : -1e30f;
  for (int t=1; t<L; ++t){
    const float e = (lane < 13) ? lg[(size_t)t*13 + lane] : 0.f;
    float v[13]; float m = -1e30f;
    #pragma unroll
    for (int i=0; i<13; ++i){ v[i] = __shfl(alpha, i) + tc[i]; m = fmaxf(m, v[i]); }
    float sum = 0.f;
    #pragma unroll
    for (int i=0; i<13; ++i) sum += __expf(v[i] - m);
    alpha = m + __logf(sum) + e;
  }
  float av = (lane < 13) ? alpha + ent[lane] : -1e30f;
  float m2 = -1e30f;
  #pragma unroll
  for (int i=0; i<13; ++i) m2 = fmaxf(m2, __shfl(av, i));
  float s2 = 0.f;
  #pragma unroll
  for (int i=0; i<13; ++i) s2 += __expf(__shfl(av, i) - m2);
  const float logz = m2 + __logf(s2);
  const int* tg = ntag + (size_t)b*S_;
  float num = 0.f;
  for (int t = lane; t < L; t += 64){
    const int cur = tg[t];
    num += lg[(size_t)t*13 + cur];
    if (t >= 1) num += trans[tg[t-1]*13 + cur];
  }
  #pragma unroll
  for (int off=32; off; off>>=1) num += __shfl_down(num, off);
  if (lane == 0){
    num += stt[tg[0]] + ent[tg[L-1]];
    ll[b] = num - logz;
  }
}

extern "C" void kernel_launch(void* const* d_in, const int* in_sizes, int n_in,
                              void* d_out, int out_size, void* d_ws, size_t ws_size,
                              hipStream_t stream){
  const float* x    = (const float*)d_in[0];
  const float* gcn  = (const float*)d_in[1];
  const int* length = (const int*)d_in[3];
  const int* tags   = (const int*)d_in[4];
  const float* wihf = (const float*)d_in[5];
  const float* whhf = (const float*)d_in[6];
  const float* bf   = (const float*)d_in[7];
  const float* wihb = (const float*)d_in[8];
  const float* whhb = (const float*)d_in[9];
  const float* bb   = (const float*)d_in[10];
  const float* mw   = (const float*)d_in[11];
  const float* mb   = (const float*)d_in[12];
  const float* trans= (const float*)d_in[13];
  const float* stt  = (const float*)d_in[14];
  const float* ent  = (const float*)d_in[15];

  char* ws = (char*)d_ws;
  ushort* nx   = (ushort*)(ws + 0);              // 33,554,432 B  new_x bf16
  __half* pre  = (__half*)(ws + 33554432);       // 134,217,728 B pre-activations f16
  float*  outh = (float*)(ws + 167772160);       // 67,108,864 B  concat h states
  ushort* wih  = (ushort*)(ws + 234881024);      // 2,097,152 B   w_ih bf16 [2048][512]
  signed char* whh8 = (signed char*)(ws + 236978176); // 524,288 B w_hh i8 [2][1024][256]
  int*    src  = (int*)(ws + 238026752);         // 131,072 B
  int*    ntag = (int*)(ws + 238157824);         // 131,072 B
  int*    cum  = (int*)(ws + 238288896);         // 4,096 B
  int*    doc  = (int*)(ws + 238292992);         // 64 B

  float* logits  = (float*)d_out;                // 425,984 floats
  float* maskout = logits + 425984;              // 32,768 floats
  float* ll      = maskout + 32768;              // 16 floats

  hipLaunchKernelGGL(k_prep,   dim3(1),        dim3(1024), 0, stream, length, cum, doc);
  hipLaunchKernelGGL(k_cast,   dim3(6144),     dim3(256),  0, stream, wihf, wihb, whhf, whhb, wih, whh8);
  hipLaunchKernelGGL(k_srcmap, dim3(128),      dim3(256),  0, stream, length, cum, tags, src, ntag);
  hipLaunchKernelGGL(k_newx,   dim3(32768),    dim3(256),  0, stream, x, gcn, src, doc, nx, maskout);
  hipLaunchKernelGGL(k_gemm,   dim3(256, 16),  dim3(256),  0, stream, nx, wih, bf, bb, doc, pre);
  hipLaunchKernelGGL(k_recur4, dim3(32),       dim3(512),  0, stream, whh8, pre, doc, outh);
  hipLaunchKernelGGL(k_logits, dim3(8192),     dim3(256),  0, stream, outh, mw, mb, doc, logits);
  hipLaunchKernelGGL(k_crf,    dim3(16),       dim3(64),   0, stream, logits, ntag, doc, trans, stt, ent, ll);
}